// Round 1
// baseline (54.545 us; speedup 1.0000x reference)
//
#include <hip/hip_runtime.h>

#define DH 40
#define DW 40
#define DT 40
#define NC 96
#define NH 6
#define HD 16
#define NTOK 27
#define NVOX (DH * DW * DT)

__global__ __launch_bounds__(256) void natt_disp_kernel(
    const float* __restrict__ q,
    const float* __restrict__ k,
    const float* __restrict__ rpb,
    float* __restrict__ out)
{
    __shared__ float s_rpb[NH * NTOK];
    if (threadIdx.x < NH * NTOK) s_rpb[threadIdx.x] = rpb[threadIdx.x];
    __syncthreads();

    int tid = blockIdx.x * blockDim.x + threadIdx.x;
    if (tid >= NVOX * NH) return;

    const int h   = tid % NH;
    const int vox = tid / NH;
    const int z = vox % DT;
    const int y = (vox / DT) % DW;
    const int x = vox / (DT * DW);

    const float scale = 0.25f;  // 16^-0.5

    // Load q fragment (16 floats), pre-scaled
    const float4* qv = (const float4*)(q + (size_t)vox * NC + h * HD);
    float4 q0 = qv[0], q1 = qv[1], q2 = qv[2], q3 = qv[3];
    q0.x *= scale; q0.y *= scale; q0.z *= scale; q0.w *= scale;
    q1.x *= scale; q1.y *= scale; q1.z *= scale; q1.w *= scale;
    q2.x *= scale; q2.y *= scale; q2.z *= scale; q2.w *= scale;
    q3.x *= scale; q3.y *= scale; q3.z *= scale; q3.w *= scale;

    float logits[NTOK];

    #pragma unroll
    for (int i = 0; i < 3; ++i) {
        #pragma unroll
        for (int j = 0; j < 3; ++j) {
            #pragma unroll
            for (int l = 0; l < 3; ++l) {
                const int kk = (i * 3 + j) * 3 + l;
                const int xx = x + i - 1;
                const int yy = y + j - 1;
                const int zz = z + l - 1;
                float dot = 0.0f;
                if (xx >= 0 && xx < DH && yy >= 0 && yy < DW && zz >= 0 && zz < DT) {
                    const float4* kv = (const float4*)(
                        k + ((size_t)((xx * DW + yy) * DT + zz)) * NC + h * HD);
                    float4 k0 = kv[0], k1 = kv[1], k2 = kv[2], k3 = kv[3];
                    dot = q0.x * k0.x + q0.y * k0.y + q0.z * k0.z + q0.w * k0.w
                        + q1.x * k1.x + q1.y * k1.y + q1.z * k1.z + q1.w * k1.w
                        + q2.x * k2.x + q2.y * k2.y + q2.z * k2.z + q2.w * k2.w
                        + q3.x * k3.x + q3.y * k3.y + q3.z * k3.z + q3.w * k3.w;
                }
                logits[kk] = dot + s_rpb[h * NTOK + kk];
            }
        }
    }

    // Softmax over 27 (in registers, fully unrolled indices)
    float m = logits[0];
    #pragma unroll
    for (int kk = 1; kk < NTOK; ++kk) m = fmaxf(m, logits[kk]);
    float sum = 0.0f;
    #pragma unroll
    for (int kk = 0; kk < NTOK; ++kk) {
        float e = __expf(logits[kk] - m);
        logits[kk] = e;
        sum += e;
    }
    const float inv = 1.0f / sum;

    // Expected displacement: offsets (i-1, j-1, l-1)
    float sx = 0.0f, sy = 0.0f, sz = 0.0f;
    #pragma unroll
    for (int i = 0; i < 3; ++i) {
        #pragma unroll
        for (int j = 0; j < 3; ++j) {
            #pragma unroll
            for (int l = 0; l < 3; ++l) {
                const float a = logits[(i * 3 + j) * 3 + l];
                sx += a * (float)(i - 1);
                sy += a * (float)(j - 1);
                sz += a * (float)(l - 1);
            }
        }
    }
    sx *= inv; sy *= inv; sz *= inv;

    // out layout: [NH*3][NVOX]
    out[((size_t)(h * 3 + 0)) * NVOX + vox] = sx;
    out[((size_t)(h * 3 + 1)) * NVOX + vox] = sy;
    out[((size_t)(h * 3 + 2)) * NVOX + vox] = sz;
}

extern "C" void kernel_launch(void* const* d_in, const int* in_sizes, int n_in,
                              void* d_out, int out_size, void* d_ws, size_t ws_size,
                              hipStream_t stream) {
    const float* q   = (const float*)d_in[0];
    const float* k   = (const float*)d_in[1];
    const float* rpb = (const float*)d_in[2];
    float* out = (float*)d_out;

    const int total = NVOX * NH;           // 384,000 threads
    const int block = 256;
    const int grid = (total + block - 1) / block;  // 1500 blocks
    natt_disp_kernel<<<grid, block, 0, stream>>>(q, k, rpb, out);
}